// Round 1
// baseline (204.015 us; speedup 1.0000x reference)
//
#include <hip/hip_runtime.h>

#define BB 4
#define HH 1024
#define WW 1024
#define K2 9
#define PAD 1

__global__ __launch_bounds__(256) void dcn_kernel(
    const float* __restrict__ init_dem,   // [B,1,H,W]
    const float* __restrict__ weight,     // [B,K2,H,W]
    const float* __restrict__ offset,     // [B,2*K2,H,W]  (dy,dx interleaved per tap)
    const float* __restrict__ wk,         // [K2] (flattened conv weight, ones)
    const float* __restrict__ bias,       // [1]
    float* __restrict__ out)              // [B,1,H,W]
{
    const int HW = HH * WW;
    int idx = blockIdx.x * blockDim.x + threadIdx.x;
    if (idx >= BB * HW) return;

    int b   = idx / HW;
    int rem = idx - b * HW;
    int h   = rem / WW;
    int w   = rem - h * WW;

    const float* img = init_dem + (size_t)b * HW;

    // --- load 9 modulation weights, compute zero-mean mask inline ---
    float wt[K2];
    float wsum = 0.f;
#pragma unroll
    for (int k = 0; k < K2; ++k) {
        wt[k] = weight[((size_t)(b * K2 + k)) * HW + rem];
        wsum += wt[k];
    }
    const float mean = wsum * (1.0f / K2);

    const float bval = bias[0];

    float acc = 0.f;
#pragma unroll
    for (int k = 0; k < K2; ++k) {
        float dy = offset[((size_t)(b * 2 * K2 + 2 * k    )) * HW + rem];
        float dx = offset[((size_t)(b * 2 * K2 + 2 * k + 1)) * HW + rem];

        float ys = (float)(h - PAD + k / 3) + dy;
        float xs = (float)(w - PAD + k % 3) + dx;

        float y0f = floorf(ys);
        float x0f = floorf(xs);
        float wy1 = ys - y0f;
        float wx1 = xs - x0f;
        float wy0 = 1.f - wy1;
        float wx0 = 1.f - wx1;

        int y0 = (int)y0f;
        int x0 = (int)x0f;
        int y1 = y0 + 1;
        int x1 = x0 + 1;

        bool y0v = (y0 >= 0) & (y0 < HH);
        bool y1v = (y1 >= 0) & (y1 < HH);
        bool x0v = (x0 >= 0) & (x0 < WW);
        bool x1v = (x1 >= 0) & (x1 < WW);

        int yc0 = min(max(y0, 0), HH - 1);
        int yc1 = min(max(y1, 0), HH - 1);
        int xc0 = min(max(x0, 0), WW - 1);
        int xc1 = min(max(x1, 0), WW - 1);

        float v00 = (y0v & x0v) ? img[(size_t)yc0 * WW + xc0] : 0.f;
        float v01 = (y0v & x1v) ? img[(size_t)yc0 * WW + xc1] : 0.f;
        float v10 = (y1v & x0v) ? img[(size_t)yc1 * WW + xc0] : 0.f;
        float v11 = (y1v & x1v) ? img[(size_t)yc1 * WW + xc1] : 0.f;

        float samp = wy0 * (wx0 * v00 + wx1 * v01)
                   + wy1 * (wx0 * v10 + wx1 * v11);

        acc += samp * (wt[k] - mean) * wk[k];
    }

    out[idx] = acc + bval + img[rem];
}

extern "C" void kernel_launch(void* const* d_in, const int* in_sizes, int n_in,
                              void* d_out, int out_size, void* d_ws, size_t ws_size,
                              hipStream_t stream) {
    const float* init_dem = (const float*)d_in[0];
    const float* weight   = (const float*)d_in[1];
    const float* offset   = (const float*)d_in[2];
    const float* wk       = (const float*)d_in[3];
    const float* bias     = (const float*)d_in[4];
    float* out            = (float*)d_out;

    const int total = BB * HH * WW;
    dim3 block(256);
    dim3 grid((total + 255) / 256);
    dcn_kernel<<<grid, block, 0, stream>>>(init_dem, weight, offset, wk, bias, out);
}

// Round 2
// 171.636 us; speedup vs baseline: 1.1886x; 1.1886x over previous
//
#include <hip/hip_runtime.h>

#define BB 4
#define HH 1024
#define WW 1024
#define K2 9
#define PAD 1

// Block = 256 threads as a 64(w) x 4(h) tile.
// Grid = 4 batches * 16(w-tiles) * 256(h-tiles) = 16384 blocks.
// XCD swizzle: blockIdx % 8 -> XCD (heuristic); batch b pinned to XCDs {2b,2b+1}
// so each XCD's 4 MiB L2 caches exactly one 4 MB image for the gathers.

__global__ __launch_bounds__(256) void dcn_kernel(
    const float* __restrict__ init_dem,   // [B,1,H,W]
    const float* __restrict__ weight,     // [B,K2,H,W]
    const float* __restrict__ offset,     // [B,2*K2,H,W]
    const float* __restrict__ wk,         // [K2]
    const float* __restrict__ bias,       // [1]
    float* __restrict__ out)              // [B,1,H,W]
{
    const int HW = HH * WW;

    int i = blockIdx.x;
    int b    = (i & 7) >> 1;                      // batch from XCD pair
    int widx = ((i >> 3) << 1) | (i & 1);         // within-batch tile id, bijective
    int tile_w = widx & 15;                       // W/64 = 16
    int tile_h = widx >> 4;                       // H/4  = 256

    int tx = threadIdx.x & 63;
    int ty = threadIdx.x >> 6;
    int w = (tile_w << 6) + tx;
    int h = (tile_h << 2) + ty;
    int rem = h * WW + w;

    const float* img = init_dem + (size_t)b * HW;
    const float* wq  = weight   + (size_t)b * K2 * HW + rem;
    const float* oq  = offset   + (size_t)b * 2 * K2 * HW + rem;

    // ---- phase 1: stream in modulation + offsets (non-temporal: read-once) ----
    float wt[K2], dy[K2], dx[K2];
    float wsum = 0.f;
#pragma unroll
    for (int k = 0; k < K2; ++k) {
        wt[k] = __builtin_nontemporal_load(wq + (size_t)k * HW);
        dy[k] = __builtin_nontemporal_load(oq + (size_t)(2 * k) * HW);
        dx[k] = __builtin_nontemporal_load(oq + (size_t)(2 * k + 1) * HW);
        wsum += wt[k];
    }
    const float mean = wsum * (1.0f / K2);

    // ---- phase 2: issue all 36 gathers (independent; keep in flight) ----
    float v00[K2], v01[K2], v10[K2], v11[K2];
    float wy1[K2], wx1[K2];
#pragma unroll
    for (int k = 0; k < K2; ++k) {
        float ys = (float)(h - PAD + k / 3) + dy[k];
        float xs = (float)(w - PAD + k % 3) + dx[k];

        float y0f = floorf(ys);
        float x0f = floorf(xs);
        wy1[k] = ys - y0f;
        wx1[k] = xs - x0f;

        int y0 = (int)y0f;
        int x0 = (int)x0f;
        int y1 = y0 + 1;
        int x1 = x0 + 1;

        bool y0v = (y0 >= 0) & (y0 < HH);
        bool y1v = (y1 >= 0) & (y1 < HH);
        bool x0v = (x0 >= 0) & (x0 < WW);
        bool x1v = (x1 >= 0) & (x1 < WW);

        int yc0 = min(max(y0, 0), HH - 1);
        int yc1 = min(max(y1, 0), HH - 1);
        int xc0 = min(max(x0, 0), WW - 1);
        int xc1 = min(max(x1, 0), WW - 1);

        v00[k] = (y0v & x0v) ? img[(size_t)yc0 * WW + xc0] : 0.f;
        v01[k] = (y0v & x1v) ? img[(size_t)yc0 * WW + xc1] : 0.f;
        v10[k] = (y1v & x0v) ? img[(size_t)yc1 * WW + xc0] : 0.f;
        v11[k] = (y1v & x1v) ? img[(size_t)yc1 * WW + xc1] : 0.f;
    }

    // ---- phase 3: combine ----
    float acc = 0.f;
#pragma unroll
    for (int k = 0; k < K2; ++k) {
        float wy0 = 1.f - wy1[k];
        float wx0 = 1.f - wx1[k];
        float samp = wy0 * (wx0 * v00[k] + wx1[k] * v01[k])
                   + wy1[k] * (wx0 * v10[k] + wx1[k] * v11[k]);
        acc += samp * (wt[k] - mean) * wk[k];
    }

    float r = acc + bias[0] + img[rem];
    __builtin_nontemporal_store(r, out + (size_t)b * HW + rem);
}

extern "C" void kernel_launch(void* const* d_in, const int* in_sizes, int n_in,
                              void* d_out, int out_size, void* d_ws, size_t ws_size,
                              hipStream_t stream) {
    const float* init_dem = (const float*)d_in[0];
    const float* weight   = (const float*)d_in[1];
    const float* offset   = (const float*)d_in[2];
    const float* wk       = (const float*)d_in[3];
    const float* bias     = (const float*)d_in[4];
    float* out            = (float*)d_out;

    const int nblocks = BB * (WW / 64) * (HH / 4);   // 16384
    dcn_kernel<<<dim3(nblocks), dim3(256), 0, stream>>>(init_dem, weight, offset, wk, bias, out);
}

// Round 3
// 102.628 us; speedup vs baseline: 1.9879x; 1.6724x over previous
//
#include <hip/hip_runtime.h>

#define BB 4
#define HH 1024
#define WW 1024
#define K2 9
#define PAD 1

#define R   12            // halo radius (covers 5-sigma offsets)
#define TW  64            // tile width
#define TH  8             // tile height (2 rows per thread)
#define RW  (TW + 2*R)    // 88
#define RH  (TH + 2*R)    // 32
#define RSZ (RW * RH)     // 2816 = 11 * 256

__global__ __launch_bounds__(256) void dcn_kernel(
    const float* __restrict__ init_dem,   // [B,1,H,W]
    const float* __restrict__ weight,     // [B,K2,H,W]
    const float* __restrict__ offset,     // [B,2*K2,H,W]
    const float* __restrict__ wk,         // [K2]
    const float* __restrict__ bias,       // [1]
    float* __restrict__ out)              // [B,1,H,W]
{
    __shared__ float region[RSZ];

    const int HW = HH * WW;

    // batch pinned to an XCD pair (blockIdx % 8 -> XCD heuristic)
    int i    = blockIdx.x;
    int b    = (i & 7) >> 1;
    int widx = ((i >> 3) << 1) | (i & 1);     // 0 .. 2047, bijective
    int tile_w = widx & 15;                   // W/TW = 16
    int tile_h = widx >> 4;                   // H/TH = 128
    int w0 = tile_w * TW;
    int h0 = tile_h * TH;

    const float* img = init_dem + (size_t)b * HW;

    // ---- stage image region (halo included, zero outside image) ----
    int tid = threadIdx.x;
#pragma unroll
    for (int it = 0; it < RSZ / 256; ++it) {
        int e = tid + it * 256;
        int r = e / RW;
        int c = e - r * RW;
        int gy = h0 - R + r;
        int gx = w0 - R + c;
        float v = 0.f;
        if ((unsigned)gy < (unsigned)HH && (unsigned)gx < (unsigned)WW)
            v = img[gy * WW + gx];
        region[e] = v;
    }
    __syncthreads();

    const int tx = tid & 63;
    const int ty = tid >> 6;
    const float bval = bias[0];

    float wgt[K2];
#pragma unroll
    for (int k = 0; k < K2; ++k) wgt[k] = wk[k];

#pragma unroll
    for (int p = 0; p < 2; ++p) {
        int h = h0 + ty + p * 4;
        int w = w0 + tx;
        int rem = h * WW + w;

        const float* wq = weight + (size_t)b * K2 * HW + rem;
        const float* oq = offset + (size_t)b * 2 * K2 * HW + rem;

        // stream in modulation + offsets (read-once -> non-temporal)
        float wt[K2], dy[K2], dx[K2];
        float wsum = 0.f;
#pragma unroll
        for (int k = 0; k < K2; ++k) {
            wt[k] = __builtin_nontemporal_load(wq + (size_t)k * HW);
            dy[k] = __builtin_nontemporal_load(oq + (size_t)(2 * k) * HW);
            dx[k] = __builtin_nontemporal_load(oq + (size_t)(2 * k + 1) * HW);
            wsum += wt[k];
        }
        const float mean = wsum * (1.0f / K2);

        float acc = 0.f;
#pragma unroll
        for (int k = 0; k < K2; ++k) {
            float ys = (float)(h - PAD + k / 3) + dy[k];
            float xs = (float)(w - PAD + k % 3) + dx[k];

            float y0f = floorf(ys);
            float x0f = floorf(xs);
            float wy1 = ys - y0f;
            float wx1 = xs - x0f;
            float wy0 = 1.f - wy1;
            float wx0 = 1.f - wx1;

            int y0g = (int)y0f;
            int x0g = (int)x0f;
            int y0l = y0g - (h0 - R);
            int x0l = x0g - (w0 - R);

            float v00, v01, v10, v11;
            bool fast = (y0l >= 0) & (y0l < RH - 1) & (x0l >= 0) & (x0l < RW - 1);
            if (fast) {
                int base = y0l * RW + x0l;
                v00 = region[base];
                v01 = region[base + 1];
                v10 = region[base + RW];
                v11 = region[base + RW + 1];
            } else {
                int y1g = y0g + 1;
                int x1g = x0g + 1;
                bool y0v = (y0g >= 0) & (y0g < HH);
                bool y1v = (y1g >= 0) & (y1g < HH);
                bool x0v = (x0g >= 0) & (x0g < WW);
                bool x1v = (x1g >= 0) & (x1g < WW);
                int yc0 = min(max(y0g, 0), HH - 1);
                int yc1 = min(max(y1g, 0), HH - 1);
                int xc0 = min(max(x0g, 0), WW - 1);
                int xc1 = min(max(x1g, 0), WW - 1);
                v00 = (y0v & x0v) ? img[(size_t)yc0 * WW + xc0] : 0.f;
                v01 = (y0v & x1v) ? img[(size_t)yc0 * WW + xc1] : 0.f;
                v10 = (y1v & x0v) ? img[(size_t)yc1 * WW + xc0] : 0.f;
                v11 = (y1v & x1v) ? img[(size_t)yc1 * WW + xc1] : 0.f;
            }

            float samp = wy0 * (wx0 * v00 + wx1 * v01)
                       + wy1 * (wx0 * v10 + wx1 * v11);
            acc += samp * (wt[k] - mean) * wgt[k];
        }

        // residual read from LDS (same values as img[rem] for in-tile pixels)
        float resid = region[(ty + p * 4 + R) * RW + (tx + R)];
        float rres = acc + bval + resid;
        __builtin_nontemporal_store(rres, out + (size_t)b * HW + rem);
    }
}

extern "C" void kernel_launch(void* const* d_in, const int* in_sizes, int n_in,
                              void* d_out, int out_size, void* d_ws, size_t ws_size,
                              hipStream_t stream) {
    const float* init_dem = (const float*)d_in[0];
    const float* weight   = (const float*)d_in[1];
    const float* offset   = (const float*)d_in[2];
    const float* wk       = (const float*)d_in[3];
    const float* bias     = (const float*)d_in[4];
    float* out            = (float*)d_out;

    const int nblocks = BB * (WW / TW) * (HH / TH);   // 4*16*128 = 8192
    dcn_kernel<<<dim3(nblocks), dim3(256), 0, stream>>>(init_dem, weight, offset, wk, bias, out);
}